// Round 10
// baseline (305.452 us; speedup 1.0000x reference)
//
#include <hip/hip_runtime.h>
#include <math.h>

#define NNODES 10000
#define NEDGES 320000
#define ETOT   (NEDGES + NNODES)
#define FINF   512
#define HD     512     // H*D
#define MAXDEG 128

typedef __attribute__((ext_vector_type(8))) _Float16 f16x8;
typedef __attribute__((ext_vector_type(8))) ushort u16x8;
typedef __attribute__((ext_vector_type(4))) float f32x4;

__device__ __forceinline__ ushort f2h(float f) {
    return __builtin_bit_cast(ushort, (_Float16)f);
}
__device__ __forceinline__ float h2f(ushort u) {
    return (float)__builtin_bit_cast(_Float16, u);
}

// ---------------- prep: transpose 4 weights to fp16 [N][K] + zero control block ----------
#define PW1 (512 * 512)                  // w_conv
#define PW2 (PW1 + 256 * 512)            // w_a
#define PW3 (PW2 + 128 * 256)            // w_1
#define PW4 (PW3 + 64 * 128)             // w_2
#define ZWORDS 50896                     // ZB bytes / 4
__global__ __launch_bounds__(256) void prep_kernel(
    const float* __restrict__ wc, ushort* __restrict__ wch,
    const float* __restrict__ wa, ushort* __restrict__ wah,
    const float* __restrict__ w1, ushort* __restrict__ w1h,
    const float* __restrict__ w2, ushort* __restrict__ w2h,
    int* __restrict__ zbuf)
{
    int idx = blockIdx.x * 256 + threadIdx.x;
    if (idx >= PW4) return;
    if (idx < ZWORDS) zbuf[idx] = 0;
    float v; ushort* th; int i;
    if (idx < PW1) {            // w_conv [512][512] -> T
        i = idx; int n = i >> 9, k = i & 511;
        v = wc[(size_t)k * 512 + n]; th = wch;
    } else if (idx < PW2) {     // w_a [512][256] -> [256][512]
        i = idx - PW1; int n = i >> 9, k = i & 511;
        v = wa[(size_t)k * 256 + n]; th = wah;
    } else if (idx < PW3) {     // w_1 [256][128] -> [128][256]
        i = idx - PW2; int n = i >> 8, k = i & 255;
        v = w1[(size_t)k * 128 + n]; th = w1h;
    } else {                    // w_2 [128][64] -> [64][128]
        i = idx - PW3; int n = i >> 7, k = i & 127;
        v = w2[(size_t)k * 64 + n]; th = w2h;
    }
    th[i] = f2h(v);
}

// ---------------- fp16-MFMA GEMM with fused A-transform / attn / BN-stats epilogues -------
// AMODE 0: A fp16 [M][K]. AMODE 1: A f32, cvt in staging. AMODE 2: A f32 + BN + lrelu.
// B: fp16 [N][K] (pre-transposed). BK=32, BM=64. 4 waves 2x2; frags MR=2 x NR=BN/32.
// OF16: C written as fp16.
template<int BN, int AMODE, bool ATTN, bool STATS, bool OF16>
__global__ __launch_bounds__(256) void gemm_f16(
    const void* __restrict__ Ain, const ushort* __restrict__ Bh,
    void* __restrict__ Cout, int M, int N, int K,
    const float* __restrict__ att_s, const float* __restrict__ att_d,
    float* __restrict__ a_src, float* __restrict__ a_dst,
    float* __restrict__ stats,
    const float* __restrict__ bnst, const float* __restrict__ bng,
    const float* __restrict__ bnbe)
{
    constexpr int BM = 64;
    constexpr int MR = 2, NR = BN / 32, BP = BN / 64;
    __shared__ ushort sA[BM][40], sB[BN][40];   // 80B row stride: 2-way bank (free)
    __shared__ float bsc[256], bsh[256];        // BN scale/shift (AMODE 2, K<=256)
    int tid = threadIdx.x;
    int lane = tid & 63, wave = tid >> 6;
    int wr = wave >> 1, wc = wave & 1;
    int bm = blockIdx.y * BM, bn = blockIdx.x * BN;
    int mrow = lane & 15, kb = lane >> 4;

    if constexpr (AMODE == 2) {
        for (int c = tid; c < K; c += 256) {
            float m = bnst[c] * (1.f / NNODES);
            float var = bnst[K + c] * (1.f / NNODES) - m * m;
            float sc = bng[c] * rsqrtf(var + 1e-5f);
            bsc[c] = sc;
            bsh[c] = bnbe[c] - m * sc;
        }
        __syncthreads();
    }

    int ar = tid >> 2, akc = tid & 3;
    int arow = bm + ar;
    bool aval = arow < M;
    size_t aoff = (size_t)(aval ? arow : 0) * K + akc * 8;
    size_t boff = (size_t)(bn + ar) * K + akc * 8;

    f32x4 acc[MR][NR];
    #pragma unroll
    for (int i = 0; i < MR; ++i)
        #pragma unroll
        for (int j = 0; j < NR; ++j)
            acc[i][j] = (f32x4){0.f, 0.f, 0.f, 0.f};

    for (int k0 = 0; k0 < K; k0 += 32) {
        int4 va;
        if constexpr (AMODE == 0) {
            va = aval ? *(const int4*)((const ushort*)Ain + aoff + k0) : (int4){0, 0, 0, 0};
        } else {
            u16x8 us = (u16x8)0;
            if (aval) {
                const float* ap = (const float*)Ain + aoff + k0;
                float4 f0 = *(const float4*)ap;
                float4 f1 = *(const float4*)(ap + 4);
                float vv[8] = {f0.x, f0.y, f0.z, f0.w, f1.x, f1.y, f1.z, f1.w};
                #pragma unroll
                for (int j = 0; j < 8; ++j) {
                    float v = vv[j];
                    if constexpr (AMODE == 2) {
                        int c = k0 + akc * 8 + j;
                        v = fmaf(v, bsc[c], bsh[c]);
                        v = (v > 0.f) ? v : 0.01f * v;
                    }
                    us[j] = f2h(v);
                }
            }
            va = __builtin_bit_cast(int4, us);
        }
        int4 vb[BP];
        #pragma unroll
        for (int p = 0; p < BP; ++p)
            vb[p] = *(const int4*)(Bh + boff + (size_t)p * 64 * K + k0);
        __syncthreads();
        *(int4*)&sA[ar][akc * 8] = va;
        #pragma unroll
        for (int p = 0; p < BP; ++p)
            *(int4*)&sB[ar + p * 64][akc * 8] = vb[p];
        __syncthreads();

        f16x8 fa[MR], fb[NR];
        #pragma unroll
        for (int fi = 0; fi < MR; ++fi)
            fa[fi] = *(const f16x8*)&sA[wr * 32 + fi * 16 + mrow][kb * 8];
        #pragma unroll
        for (int fj = 0; fj < NR; ++fj)
            fb[fj] = *(const f16x8*)&sB[wc * (BN / 2) + fj * 16 + mrow][kb * 8];
        #pragma unroll
        for (int fi = 0; fi < MR; ++fi)
            #pragma unroll
            for (int fj = 0; fj < NR; ++fj)
                acc[fi][fj] = __builtin_amdgcn_mfma_f32_16x16x32_f16(fa[fi], fb[fj], acc[fi][fj], 0, 0, 0);
    }

    // C write: row = bm + wr*32 + fi*16 + (lane>>4)*4 + r ; col = bn + wc*(BN/2) + fj*16 + mrow
    #pragma unroll
    for (int fi = 0; fi < MR; ++fi) {
        int crow0 = bm + wr * 32 + fi * 16 + (lane >> 4) * 4;
        #pragma unroll
        for (int fj = 0; fj < NR; ++fj) {
            int ccol = bn + wc * (BN / 2) + fj * 16 + mrow;
            #pragma unroll
            for (int r = 0; r < 4; ++r) {
                int row = crow0 + r;
                if (row < M) {
                    if constexpr (OF16)
                        ((ushort*)Cout)[(size_t)row * N + ccol] = f2h(acc[fi][fj][r]);
                    else
                        ((float*)Cout)[(size_t)row * N + ccol] = acc[fi][fj][r];
                }
            }
        }
    }

    if constexpr (ATTN) {
        int hd = (bn + wc * (BN / 2)) >> 8;
        float as_v[NR], ad_v[NR];
        #pragma unroll
        for (int fj = 0; fj < NR; ++fj) {
            int c = bn + wc * (BN / 2) + fj * 16 + mrow;
            as_v[fj] = att_s[c];
            ad_v[fj] = att_d[c];
        }
        #pragma unroll
        for (int fi = 0; fi < MR; ++fi)
            #pragma unroll
            for (int r = 0; r < 4; ++r) {
                float ss = 0.f, sd = 0.f;
                #pragma unroll
                for (int fj = 0; fj < NR; ++fj) {
                    float v = acc[fi][fj][r];
                    ss = fmaf(v, as_v[fj], ss);
                    sd = fmaf(v, ad_v[fj], sd);
                }
                #pragma unroll
                for (int off = 1; off < 16; off <<= 1) {
                    ss += __shfl_xor(ss, off);
                    sd += __shfl_xor(sd, off);
                }
                if (mrow == 0) {
                    int row = bm + wr * 32 + fi * 16 + (lane >> 4) * 4 + r;
                    if (row < M) {
                        atomicAdd(&a_src[2 * row + hd], ss);
                        atomicAdd(&a_dst[2 * row + hd], sd);
                    }
                }
            }
    }

    if constexpr (STATS) {
        #pragma unroll
        for (int fj = 0; fj < NR; ++fj) {
            float s = 0.f, s2 = 0.f;
            #pragma unroll
            for (int fi = 0; fi < MR; ++fi)
                #pragma unroll
                for (int r = 0; r < 4; ++r) {
                    float v = acc[fi][fj][r];
                    s += v;
                    s2 = fmaf(v, v, s2);
                }
            s  += __shfl_xor(s, 16);  s  += __shfl_xor(s, 32);
            s2 += __shfl_xor(s2, 16); s2 += __shfl_xor(s2, 32);
            if (lane < 16) {
                int c = bn + wc * (BN / 2) + fj * 16 + lane;
                atomicAdd(&stats[c], s);
                atomicAdd(&stats[N + c], s2);
            }
        }
    }
}

// ---------------- scatter edges into fixed-stride buckets; p = exp(lrelu(e)) ----------
__global__ __launch_bounds__(256) void scatter_kernel(const int* __restrict__ ei,
    const float* __restrict__ a_src, const float* __restrict__ a_dst,
    int* __restrict__ cnt, int* __restrict__ esrc,
    float* __restrict__ p0, float* __restrict__ p1)
{
    int e = blockIdx.x * 256 + threadIdx.x;
    if (e >= ETOT) return;
    int s, d;
    if (e < NEDGES) { s = ei[e]; d = ei[NEDGES + e]; } else { s = d = e - NEDGES; }
    int pos = atomicAdd(&cnt[d], 1);
    if (pos >= MAXDEG) return;   // statistically impossible for this graph
    int slot = d * MAXDEG + pos;
    esrc[slot] = s;
    float e0 = a_src[2 * s] + a_dst[2 * d];
    e0 = (e0 > 0.f) ? e0 : 0.2f * e0;
    float e1 = a_src[2 * s + 1] + a_dst[2 * d + 1];
    e1 = (e1 > 0.f) ? e1 : 0.2f * e1;
    p0[slot] = expf(e0);
    p1[slot] = expf(e1);
}

// ---------------- per-node aggregation (fp16 h) -> lrelu -> fp16 y ----------------
// 128 threads: thread t owns features [4t,4t+4); t<64 = head0 (p0), t>=64 = head1 (p1).
__global__ __launch_bounds__(128) void aggregate_kernel(const ushort* __restrict__ h,
    const int* __restrict__ cnt, const int* __restrict__ esrc,
    const float* __restrict__ p0, const float* __restrict__ p1,
    const float* __restrict__ b_conv, ushort* __restrict__ yh)
{
    int n = blockIdx.x, t = threadIdx.x;
    int len = cnt[n]; if (len > MAXDEG) len = MAXDEG;
    int base = n * MAXDEG;
    const float* pp = (t < 64) ? p0 : p1;
    float a0 = 0.f, a1 = 0.f, a2 = 0.f, a3 = 0.f;
    float den = 0.f;
    for (int k = 0; k < len; ++k) {
        int src = esrc[base + k];
        float q = pp[base + k];
        ushort4 hv = ((const ushort4*)(h + (size_t)src * HD))[t];
        a0 = fmaf(q, h2f(hv.x), a0);
        a1 = fmaf(q, h2f(hv.y), a1);
        a2 = fmaf(q, h2f(hv.z), a2);
        a3 = fmaf(q, h2f(hv.w), a3);
        den += q;
    }
    float4 bc = *(const float4*)(b_conv + t * 4);
    float inv = 1.f / den;
    float o[4] = { a0 * inv + bc.x, a1 * inv + bc.y, a2 * inv + bc.z, a3 * inv + bc.w };
    ushort4 hq;
    float v;
    v = (o[0] > 0.f) ? o[0] : 0.01f * o[0]; hq.x = f2h(v);
    v = (o[1] > 0.f) ? o[1] : 0.01f * o[1]; hq.y = f2h(v);
    v = (o[2] > 0.f) ? o[2] : 0.01f * o[2]; hq.z = f2h(v);
    v = (o[3] > 0.f) ? o[3] : 0.01f * o[3]; hq.w = f2h(v);
    ((ushort4*)(yh + (size_t)n * HD))[t] = hq;
}

// ---------------- BN(64) + lrelu + dense3 fused -> y3 ----------------
__global__ __launch_bounds__(256) void bn_dense3(const float* __restrict__ z2,
    const float* __restrict__ st, const float* __restrict__ g, const float* __restrict__ beta,
    const float* __restrict__ w3, const float* __restrict__ b3, float* __restrict__ y3)
{
    __shared__ float wsm[192], msm[64], rsm[64], gsm[64], bsm[64];
    int t = threadIdx.x;
    if (t < 192) wsm[t] = w3[t];
    if (t < 64) {
        float m = st[t] * (1.f / NNODES);
        float v = st[64 + t] * (1.f / NNODES) - m * m;
        msm[t] = m; rsm[t] = rsqrtf(v + 1e-5f);
        gsm[t] = g[t]; bsm[t] = beta[t];
    }
    __syncthreads();
    int n = blockIdx.x * 256 + t;
    if (n >= NNODES) return;
    const float* zr = z2 + (size_t)n * 64;
    float o0 = b3[0], o1 = b3[1], o2 = b3[2];
    #pragma unroll
    for (int c = 0; c < 64; ++c) {
        float xv = zr[c];
        xv = gsm[c] * (xv - msm[c]) * rsm[c] + bsm[c];
        xv = (xv > 0.f) ? xv : 0.01f * xv;
        o0 = fmaf(xv, wsm[3 * c],     o0);
        o1 = fmaf(xv, wsm[3 * c + 1], o1);
        o2 = fmaf(xv, wsm[3 * c + 2], o2);
    }
    y3[3 * n] = o0; y3[3 * n + 1] = o1; y3[3 * n + 2] = o2;
}

// ---------------- pairwise euclidean distances [N,N], 4 cols/thread, NT f32x4 stores ----
__global__ __launch_bounds__(256) void dist_kernel(const float* __restrict__ y3, float* __restrict__ out)
{
    int j0 = (blockIdx.x * 256 + threadIdx.x) * 4;
    int i0 = blockIdx.y * 64;
    if (j0 >= NNODES) return;
    const float4* yp = (const float4*)(y3 + 3 * j0);
    float4 q0 = yp[0], q1 = yp[1], q2 = yp[2];
    float xj[4] = {q0.x, q0.w, q1.z, q2.y};
    float yj[4] = {q0.y, q1.x, q1.w, q2.z};
    float zj[4] = {q0.z, q1.y, q2.x, q2.w};
    int iend = (i0 + 64 < NNODES) ? (i0 + 64) : NNODES;
    for (int i = i0; i < iend; ++i) {
        float xi = y3[3 * i], yi = y3[3 * i + 1], zi = y3[3 * i + 2];
        f32x4 dv;
        #pragma unroll
        for (int u = 0; u < 4; ++u) {
            float dx = xi - xj[u], dy = yi - yj[u], dz = zi - zj[u];
            float d2 = fmaf(dx, dx, fmaf(dy, dy, dz * dz));
            dv[u] = (d2 > 1e-12f) ? sqrtf(d2) : 0.f;
        }
        __builtin_nontemporal_store(dv, (f32x4*)(out + (size_t)i * NNODES + j0));
    }
}

extern "C" void kernel_launch(void* const* d_in, const int* in_sizes, int n_in,
                              void* d_out, int out_size, void* d_ws, size_t ws_size,
                              hipStream_t stream)
{
    (void)in_sizes; (void)n_in; (void)out_size; (void)ws_size;
    const float* x      = (const float*)d_in[0];
    const int*   ei     = (const int*)  d_in[1];
    const float* w_conv = (const float*)d_in[2];
    const float* att_s  = (const float*)d_in[3];
    const float* att_d  = (const float*)d_in[4];
    const float* b_conv = (const float*)d_in[5];
    const float* w_a  = (const float*)d_in[6];
    const float* g_a  = (const float*)d_in[8];
    const float* be_a = (const float*)d_in[9];
    const float* w_1  = (const float*)d_in[10];
    const float* g_1  = (const float*)d_in[12];
    const float* be_1 = (const float*)d_in[13];
    const float* w_2  = (const float*)d_in[14];
    const float* g_2  = (const float*)d_in[16];
    const float* be_2 = (const float*)d_in[17];
    const float* w_3  = (const float*)d_in[18];
    const float* b_3  = (const float*)d_in[19];

    char* ws = (char*)d_ws;
    size_t off = 0;
    auto take = [&](size_t bytes) {
        char* p = ws + off;
        off = (off + bytes + 255) & ~(size_t)255;
        return p;
    };
    ushort* h   = (ushort*)take((size_t)NNODES * HD * 2);      // fp16 h
    ushort* yh  = (ushort*)take((size_t)NNODES * HD * 2);      // fp16 y
    float* z_a  = (float*)take((size_t)NNODES * 256 * 4);
    float* z_1  = (float*)take((size_t)NNODES * 128 * 4);
    float* z_2  = (float*)take((size_t)NNODES * 64 * 4);
    float* y3   = (float*)take((size_t)NNODES * 3 * 4);
    ushort* wch = (ushort*)take((size_t)512 * 512 * 2);
    ushort* wah = (ushort*)take((size_t)256 * 512 * 2);
    ushort* w1h = (ushort*)take((size_t)128 * 256 * 2);
    ushort* w2h = (ushort*)take((size_t)64 * 128 * 2);
    int*   esrc = (int*)  take((size_t)NNODES * MAXDEG * 4);
    float* p0   = (float*)take((size_t)NNODES * MAXDEG * 4);
    float* p1   = (float*)take((size_t)NNODES * MAXDEG * 4);
    // zeroed-by-prep block: cnt, stats x3, a_src, a_dst  (ZWORDS*4 bytes total)
    const size_t ZB = 40000 + 2048 + 1024 + 512 + 80000 + 80000;   // 203584 = 50896*4
    char*  zblk = take(ZB);
    int*   cnt  = (int*)(zblk);
    float* stA  = (float*)(zblk + 40000);
    float* st1  = (float*)(zblk + 42048);
    float* st2  = (float*)(zblk + 43072);
    float* a_src= (float*)(zblk + 43584);
    float* a_dst= (float*)(zblk + 123584);

    dim3 b256(256), b128(128);
    const int MT = (NNODES + 63) / 64;   // 157

    // weights -> fp16 transposed, + zero control block
    prep_kernel<<<dim3((PW4 + 255) / 256), b256, 0, stream>>>(
        w_conv, wch, w_a, wah, w_1, w1h, w_2, w2h, (int*)zblk);

    // h = x @ w_conv (fp16 out, x converted in staging), fused attn coefficients
    gemm_f16<256, 1, true, false, true><<<dim3(HD / 256, MT), b256, 0, stream>>>(
        x, wch, h, NNODES, HD, FINF, att_s, att_d, a_src, a_dst, nullptr,
        nullptr, nullptr, nullptr);

    scatter_kernel<<<dim3((ETOT + 255) / 256), b256, 0, stream>>>(
        ei, a_src, a_dst, cnt, esrc, p0, p1);

    aggregate_kernel<<<dim3(NNODES), b128, 0, stream>>>(
        h, cnt, esrc, p0, p1, b_conv, yh);

    // densea 512->256 (A = y fp16), stats fused
    gemm_f16<256, 0, false, true, false><<<dim3(256 / 256, MT), b256, 0, stream>>>(
        yh, wah, z_a, NNODES, 256, 512, nullptr, nullptr, nullptr, nullptr, stA,
        nullptr, nullptr, nullptr);

    // dense1 256->128 (A = BN(z_a)+lrelu in staging), stats fused
    gemm_f16<128, 2, false, true, false><<<dim3(128 / 128, MT), b256, 0, stream>>>(
        z_a, w1h, z_1, NNODES, 128, 256, nullptr, nullptr, nullptr, nullptr, st1,
        stA, g_a, be_a);

    // dense2 128->64 (A = BN(z_1)+lrelu in staging), stats fused
    gemm_f16<64, 2, false, true, false><<<dim3(64 / 64, MT), b256, 0, stream>>>(
        z_1, w2h, z_2, NNODES, 64, 128, nullptr, nullptr, nullptr, nullptr, st2,
        st1, g_1, be_1);

    // BN + lrelu + dense3 fused
    bn_dense3<<<dim3((NNODES + 255) / 256), b256, 0, stream>>>(z_2, st2, g_2, be_2, w_3, b_3, y3);

    // pairwise distances
    dist_kernel<<<dim3((NNODES + 1023) / 1024, (NNODES + 63) / 64), b256, 0, stream>>>(y3, (float*)d_out);
}

// Round 11
// 258.660 us; speedup vs baseline: 1.1809x; 1.1809x over previous
//
#include <hip/hip_runtime.h>
#include <math.h>

#define NNODES 10000
#define NEDGES 320000
#define ETOT   (NEDGES + NNODES)
#define FINF   512
#define HD     512     // H*D
#define MAXDEG 128

typedef __attribute__((ext_vector_type(8))) _Float16 f16x8;
typedef __attribute__((ext_vector_type(8))) ushort u16x8;
typedef __attribute__((ext_vector_type(4))) float f32x4;

__device__ __forceinline__ ushort f2h(float f) {
    return __builtin_bit_cast(ushort, (_Float16)f);
}
__device__ __forceinline__ float h2f(ushort u) {
    return (float)__builtin_bit_cast(_Float16, u);
}

// ---------------- prep: transpose 4 weights to fp16 [N][K] + zero control block ----------
#define PW1 (512 * 512)                  // w_conv
#define PW2 (PW1 + 256 * 512)            // w_a
#define PW3 (PW2 + 128 * 256)            // w_1
#define PW4 (PW3 + 64 * 128)             // w_2
#define ZWORDS 50896                     // ZB bytes / 4
__global__ __launch_bounds__(256) void prep_kernel(
    const float* __restrict__ wc, ushort* __restrict__ wch,
    const float* __restrict__ wa, ushort* __restrict__ wah,
    const float* __restrict__ w1, ushort* __restrict__ w1h,
    const float* __restrict__ w2, ushort* __restrict__ w2h,
    int* __restrict__ zbuf)
{
    int idx = blockIdx.x * 256 + threadIdx.x;
    if (idx >= PW4) return;
    if (idx < ZWORDS) zbuf[idx] = 0;
    float v; ushort* th; int i;
    if (idx < PW1) {            // w_conv [512][512] -> T
        i = idx; int n = i >> 9, k = i & 511;
        v = wc[(size_t)k * 512 + n]; th = wch;
    } else if (idx < PW2) {     // w_a [512][256] -> [256][512]
        i = idx - PW1; int n = i >> 9, k = i & 511;
        v = wa[(size_t)k * 256 + n]; th = wah;
    } else if (idx < PW3) {     // w_1 [256][128] -> [128][256]
        i = idx - PW2; int n = i >> 8, k = i & 255;
        v = w1[(size_t)k * 128 + n]; th = w1h;
    } else {                    // w_2 [128][64] -> [64][128]
        i = idx - PW3; int n = i >> 7, k = i & 127;
        v = w2[(size_t)k * 64 + n]; th = w2h;
    }
    th[i] = f2h(v);
}

// ---------------- fp16-MFMA GEMM with fused A-transform / attn / BN-stats epilogues -------
// AMODE 0: A fp16 [M][K]. AMODE 1: A f32, cvt in staging. AMODE 2: A f32 + BN + lrelu.
// B: fp16 [N][K] (pre-transposed). BK=32, BM=64. 4 waves 2x2; frags MR=2 x NR=BN/32.
// OF16: C written as fp16.
template<int BN, int AMODE, bool ATTN, bool STATS, bool OF16>
__global__ __launch_bounds__(256) void gemm_f16(
    const void* __restrict__ Ain, const ushort* __restrict__ Bh,
    void* __restrict__ Cout, int M, int N, int K,
    const float* __restrict__ att_s, const float* __restrict__ att_d,
    float* __restrict__ a_src, float* __restrict__ a_dst,
    float* __restrict__ stats,
    const float* __restrict__ bnst, const float* __restrict__ bng,
    const float* __restrict__ bnbe)
{
    constexpr int BM = 64;
    constexpr int MR = 2, NR = BN / 32;
    __shared__ ushort sA[BM][40], sB[BN][40];   // 80B row stride: 2-way bank (free)
    __shared__ float bsc[256], bsh[256];        // BN scale/shift (AMODE 2, K<=256)
    int tid = threadIdx.x;
    int lane = tid & 63, wave = tid >> 6;
    int wr = wave >> 1, wc = wave & 1;
    int bm = blockIdx.y * BM, bn = blockIdx.x * BN;
    int mrow = lane & 15, kb = lane >> 4;

    if constexpr (AMODE == 2) {
        for (int c = tid; c < K; c += 256) {
            float m = bnst[c] * (1.f / NNODES);
            float var = bnst[K + c] * (1.f / NNODES) - m * m;
            float sc = bng[c] * rsqrtf(var + 1e-5f);
            bsc[c] = sc;
            bsh[c] = bnbe[c] - m * sc;
        }
        __syncthreads();
    }

    int ar = tid >> 2, akc = tid & 3;
    int arow = bm + ar;
    bool aval = arow < M;
    size_t aoff = (size_t)(aval ? arow : 0) * K + akc * 8;
    int br, bkc;
    if constexpr (BN == 128) { br = tid >> 1; bkc = (tid & 1) * 2; }
    else { br = tid >> 2; bkc = tid & 3; }
    size_t boff = (size_t)(bn + br) * K + bkc * 8;

    f32x4 acc[MR][NR];
    #pragma unroll
    for (int i = 0; i < MR; ++i)
        #pragma unroll
        for (int j = 0; j < NR; ++j)
            acc[i][j] = (f32x4){0.f, 0.f, 0.f, 0.f};

    for (int k0 = 0; k0 < K; k0 += 32) {
        int4 va;
        if constexpr (AMODE == 0) {
            va = aval ? *(const int4*)((const ushort*)Ain + aoff + k0) : (int4){0, 0, 0, 0};
        } else {
            u16x8 us = (u16x8)0;
            if (aval) {
                const float* ap = (const float*)Ain + aoff + k0;
                float4 f0 = *(const float4*)ap;
                float4 f1 = *(const float4*)(ap + 4);
                float vv[8] = {f0.x, f0.y, f0.z, f0.w, f1.x, f1.y, f1.z, f1.w};
                #pragma unroll
                for (int j = 0; j < 8; ++j) {
                    float v = vv[j];
                    if constexpr (AMODE == 2) {
                        int c = k0 + akc * 8 + j;
                        v = fmaf(v, bsc[c], bsh[c]);
                        v = (v > 0.f) ? v : 0.01f * v;
                    }
                    us[j] = f2h(v);
                }
            }
            va = __builtin_bit_cast(int4, us);
        }
        int4 vb0 = *(const int4*)(Bh + boff + k0);
        int4 vb1;
        if constexpr (BN == 128) vb1 = *(const int4*)(Bh + boff + k0 + 8);
        __syncthreads();
        *(int4*)&sA[ar][akc * 8] = va;
        *(int4*)&sB[br][bkc * 8] = vb0;
        if constexpr (BN == 128) *(int4*)&sB[br][(bkc + 1) * 8] = vb1;
        __syncthreads();

        f16x8 fa[MR], fb[NR];
        #pragma unroll
        for (int fi = 0; fi < MR; ++fi)
            fa[fi] = *(const f16x8*)&sA[wr * 32 + fi * 16 + mrow][kb * 8];
        #pragma unroll
        for (int fj = 0; fj < NR; ++fj)
            fb[fj] = *(const f16x8*)&sB[wc * (BN / 2) + fj * 16 + mrow][kb * 8];
        #pragma unroll
        for (int fi = 0; fi < MR; ++fi)
            #pragma unroll
            for (int fj = 0; fj < NR; ++fj)
                acc[fi][fj] = __builtin_amdgcn_mfma_f32_16x16x32_f16(fa[fi], fb[fj], acc[fi][fj], 0, 0, 0);
    }

    // C write: row = bm + wr*32 + fi*16 + (lane>>4)*4 + r ; col = bn + wc*(BN/2) + fj*16 + mrow
    #pragma unroll
    for (int fi = 0; fi < MR; ++fi) {
        int crow0 = bm + wr * 32 + fi * 16 + (lane >> 4) * 4;
        #pragma unroll
        for (int fj = 0; fj < NR; ++fj) {
            int ccol = bn + wc * (BN / 2) + fj * 16 + mrow;
            #pragma unroll
            for (int r = 0; r < 4; ++r) {
                int row = crow0 + r;
                if (row < M) {
                    if constexpr (OF16)
                        ((ushort*)Cout)[(size_t)row * N + ccol] = f2h(acc[fi][fj][r]);
                    else
                        ((float*)Cout)[(size_t)row * N + ccol] = acc[fi][fj][r];
                }
            }
        }
    }

    if constexpr (ATTN) {
        int hd = bn >> 8;
        float as_v[NR], ad_v[NR];
        #pragma unroll
        for (int fj = 0; fj < NR; ++fj) {
            int c = bn + wc * (BN / 2) + fj * 16 + mrow;
            as_v[fj] = att_s[c];
            ad_v[fj] = att_d[c];
        }
        #pragma unroll
        for (int fi = 0; fi < MR; ++fi)
            #pragma unroll
            for (int r = 0; r < 4; ++r) {
                float ss = 0.f, sd = 0.f;
                #pragma unroll
                for (int fj = 0; fj < NR; ++fj) {
                    float v = acc[fi][fj][r];
                    ss = fmaf(v, as_v[fj], ss);
                    sd = fmaf(v, ad_v[fj], sd);
                }
                #pragma unroll
                for (int off = 1; off < 16; off <<= 1) {
                    ss += __shfl_xor(ss, off);
                    sd += __shfl_xor(sd, off);
                }
                if (mrow == 0) {
                    int row = bm + wr * 32 + fi * 16 + (lane >> 4) * 4 + r;
                    if (row < M) {
                        atomicAdd(&a_src[2 * row + hd], ss);
                        atomicAdd(&a_dst[2 * row + hd], sd);
                    }
                }
            }
    }

    if constexpr (STATS) {
        #pragma unroll
        for (int fj = 0; fj < NR; ++fj) {
            float s = 0.f, s2 = 0.f;
            #pragma unroll
            for (int fi = 0; fi < MR; ++fi)
                #pragma unroll
                for (int r = 0; r < 4; ++r) {
                    float v = acc[fi][fj][r];
                    s += v;
                    s2 = fmaf(v, v, s2);
                }
            s  += __shfl_xor(s, 16);  s  += __shfl_xor(s, 32);
            s2 += __shfl_xor(s2, 16); s2 += __shfl_xor(s2, 32);
            if (lane < 16) {
                int c = bn + wc * (BN / 2) + fj * 16 + lane;
                atomicAdd(&stats[c], s);
                atomicAdd(&stats[N + c], s2);
            }
        }
    }
}

// ---------------- scatter edges into fixed-stride buckets; p = exp(lrelu(e)) ----------
__global__ __launch_bounds__(256) void scatter_kernel(const int* __restrict__ ei,
    const float* __restrict__ a_src, const float* __restrict__ a_dst,
    int* __restrict__ cnt, int* __restrict__ esrc,
    float* __restrict__ p0, float* __restrict__ p1)
{
    int e = blockIdx.x * 256 + threadIdx.x;
    if (e >= ETOT) return;
    int s, d;
    if (e < NEDGES) { s = ei[e]; d = ei[NEDGES + e]; } else { s = d = e - NEDGES; }
    int pos = atomicAdd(&cnt[d], 1);
    if (pos >= MAXDEG) return;   // statistically impossible for this graph
    int slot = d * MAXDEG + pos;
    esrc[slot] = s;
    float e0 = a_src[2 * s] + a_dst[2 * d];
    e0 = (e0 > 0.f) ? e0 : 0.2f * e0;
    float e1 = a_src[2 * s + 1] + a_dst[2 * d + 1];
    e1 = (e1 > 0.f) ? e1 : 0.2f * e1;
    p0[slot] = expf(e0);
    p1[slot] = expf(e1);
}

// ---------------- per-node aggregation (fp16 h) -> lrelu -> fp16 y ----------------
// 128 threads: thread t owns features [4t,4t+4); t<64 = head0 (p0), t>=64 = head1 (p1).
__global__ __launch_bounds__(128) void aggregate_kernel(const ushort* __restrict__ h,
    const int* __restrict__ cnt, const int* __restrict__ esrc,
    const float* __restrict__ p0, const float* __restrict__ p1,
    const float* __restrict__ b_conv, ushort* __restrict__ yh)
{
    int n = blockIdx.x, t = threadIdx.x;
    int len = cnt[n]; if (len > MAXDEG) len = MAXDEG;
    int base = n * MAXDEG;
    const float* pp = (t < 64) ? p0 : p1;
    float a0 = 0.f, a1 = 0.f, a2 = 0.f, a3 = 0.f;
    float den = 0.f;
    for (int k = 0; k < len; ++k) {
        int src = esrc[base + k];
        float q = pp[base + k];
        ushort4 hv = ((const ushort4*)(h + (size_t)src * HD))[t];
        a0 = fmaf(q, h2f(hv.x), a0);
        a1 = fmaf(q, h2f(hv.y), a1);
        a2 = fmaf(q, h2f(hv.z), a2);
        a3 = fmaf(q, h2f(hv.w), a3);
        den += q;
    }
    float4 bc = *(const float4*)(b_conv + t * 4);
    float inv = 1.f / den;
    float o[4] = { a0 * inv + bc.x, a1 * inv + bc.y, a2 * inv + bc.z, a3 * inv + bc.w };
    ushort4 hq;
    float v;
    v = (o[0] > 0.f) ? o[0] : 0.01f * o[0]; hq.x = f2h(v);
    v = (o[1] > 0.f) ? o[1] : 0.01f * o[1]; hq.y = f2h(v);
    v = (o[2] > 0.f) ? o[2] : 0.01f * o[2]; hq.z = f2h(v);
    v = (o[3] > 0.f) ? o[3] : 0.01f * o[3]; hq.w = f2h(v);
    ((ushort4*)(yh + (size_t)n * HD))[t] = hq;
}

// ---------------- BN(64) + lrelu + dense3 fused -> y3 ----------------
__global__ __launch_bounds__(256) void bn_dense3(const float* __restrict__ z2,
    const float* __restrict__ st, const float* __restrict__ g, const float* __restrict__ beta,
    const float* __restrict__ w3, const float* __restrict__ b3, float* __restrict__ y3)
{
    __shared__ float wsm[192], msm[64], rsm[64], gsm[64], bsm[64];
    int t = threadIdx.x;
    if (t < 192) wsm[t] = w3[t];
    if (t < 64) {
        float m = st[t] * (1.f / NNODES);
        float v = st[64 + t] * (1.f / NNODES) - m * m;
        msm[t] = m; rsm[t] = rsqrtf(v + 1e-5f);
        gsm[t] = g[t]; bsm[t] = beta[t];
    }
    __syncthreads();
    int n = blockIdx.x * 256 + t;
    if (n >= NNODES) return;
    const float* zr = z2 + (size_t)n * 64;
    float o0 = b3[0], o1 = b3[1], o2 = b3[2];
    #pragma unroll
    for (int c = 0; c < 64; ++c) {
        float xv = zr[c];
        xv = gsm[c] * (xv - msm[c]) * rsm[c] + bsm[c];
        xv = (xv > 0.f) ? xv : 0.01f * xv;
        o0 = fmaf(xv, wsm[3 * c],     o0);
        o1 = fmaf(xv, wsm[3 * c + 1], o1);
        o2 = fmaf(xv, wsm[3 * c + 2], o2);
    }
    y3[3 * n] = o0; y3[3 * n + 1] = o1; y3[3 * n + 2] = o2;
}

// ---------------- pairwise euclidean distances [N,N], 4 cols/thread, NT f32x4 stores ----
__global__ __launch_bounds__(256) void dist_kernel(const float* __restrict__ y3, float* __restrict__ out)
{
    int j0 = (blockIdx.x * 256 + threadIdx.x) * 4;
    int i0 = blockIdx.y * 64;
    if (j0 >= NNODES) return;
    const float4* yp = (const float4*)(y3 + 3 * j0);
    float4 q0 = yp[0], q1 = yp[1], q2 = yp[2];
    float xj[4] = {q0.x, q0.w, q1.z, q2.y};
    float yj[4] = {q0.y, q1.x, q1.w, q2.z};
    float zj[4] = {q0.z, q1.y, q2.x, q2.w};
    int iend = (i0 + 64 < NNODES) ? (i0 + 64) : NNODES;
    for (int i = i0; i < iend; ++i) {
        float xi = y3[3 * i], yi = y3[3 * i + 1], zi = y3[3 * i + 2];
        f32x4 dv;
        #pragma unroll
        for (int u = 0; u < 4; ++u) {
            float dx = xi - xj[u], dy = yi - yj[u], dz = zi - zj[u];
            float d2 = fmaf(dx, dx, fmaf(dy, dy, dz * dz));
            dv[u] = (d2 > 1e-12f) ? sqrtf(d2) : 0.f;
        }
        __builtin_nontemporal_store(dv, (f32x4*)(out + (size_t)i * NNODES + j0));
    }
}

extern "C" void kernel_launch(void* const* d_in, const int* in_sizes, int n_in,
                              void* d_out, int out_size, void* d_ws, size_t ws_size,
                              hipStream_t stream)
{
    (void)in_sizes; (void)n_in; (void)out_size; (void)ws_size;
    const float* x      = (const float*)d_in[0];
    const int*   ei     = (const int*)  d_in[1];
    const float* w_conv = (const float*)d_in[2];
    const float* att_s  = (const float*)d_in[3];
    const float* att_d  = (const float*)d_in[4];
    const float* b_conv = (const float*)d_in[5];
    const float* w_a  = (const float*)d_in[6];
    const float* g_a  = (const float*)d_in[8];
    const float* be_a = (const float*)d_in[9];
    const float* w_1  = (const float*)d_in[10];
    const float* g_1  = (const float*)d_in[12];
    const float* be_1 = (const float*)d_in[13];
    const float* w_2  = (const float*)d_in[14];
    const float* g_2  = (const float*)d_in[16];
    const float* be_2 = (const float*)d_in[17];
    const float* w_3  = (const float*)d_in[18];
    const float* b_3  = (const float*)d_in[19];

    char* ws = (char*)d_ws;
    size_t off = 0;
    auto take = [&](size_t bytes) {
        char* p = ws + off;
        off = (off + bytes + 255) & ~(size_t)255;
        return p;
    };
    ushort* h   = (ushort*)take((size_t)NNODES * HD * 2);      // fp16 h
    ushort* yh  = (ushort*)take((size_t)NNODES * HD * 2);      // fp16 y
    float* z_a  = (float*)take((size_t)NNODES * 256 * 4);
    float* z_1  = (float*)take((size_t)NNODES * 128 * 4);
    float* z_2  = (float*)take((size_t)NNODES * 64 * 4);
    float* y3   = (float*)take((size_t)NNODES * 3 * 4);
    ushort* wch = (ushort*)take((size_t)512 * 512 * 2);
    ushort* wah = (ushort*)take((size_t)256 * 512 * 2);
    ushort* w1h = (ushort*)take((size_t)128 * 256 * 2);
    ushort* w2h = (ushort*)take((size_t)64 * 128 * 2);
    int*   esrc = (int*)  take((size_t)NNODES * MAXDEG * 4);
    float* p0   = (float*)take((size_t)NNODES * MAXDEG * 4);
    float* p1   = (float*)take((size_t)NNODES * MAXDEG * 4);
    // zeroed-by-prep block: cnt, stats x3, a_src, a_dst  (ZWORDS*4 bytes total)
    const size_t ZB = 40000 + 2048 + 1024 + 512 + 80000 + 80000;   // 203584 = 50896*4
    char*  zblk = take(ZB);
    int*   cnt  = (int*)(zblk);
    float* stA  = (float*)(zblk + 40000);
    float* st1  = (float*)(zblk + 42048);
    float* st2  = (float*)(zblk + 43072);
    float* a_src= (float*)(zblk + 43584);
    float* a_dst= (float*)(zblk + 123584);

    dim3 b256(256), b128(128);
    const int MT = (NNODES + 63) / 64;   // 157

    // weights -> fp16 transposed, + zero control block
    prep_kernel<<<dim3((PW4 + 255) / 256), b256, 0, stream>>>(
        w_conv, wch, w_a, wah, w_1, w1h, w_2, w2h, (int*)zblk);

    // h = x @ w_conv (fp16 out, x converted in staging), fused attn coefficients
    gemm_f16<128, 1, true, false, true><<<dim3(HD / 128, MT), b256, 0, stream>>>(
        x, wch, h, NNODES, HD, FINF, att_s, att_d, a_src, a_dst, nullptr,
        nullptr, nullptr, nullptr);

    scatter_kernel<<<dim3((ETOT + 255) / 256), b256, 0, stream>>>(
        ei, a_src, a_dst, cnt, esrc, p0, p1);

    aggregate_kernel<<<dim3(NNODES), b128, 0, stream>>>(
        h, cnt, esrc, p0, p1, b_conv, yh);

    // densea 512->256 (A = y fp16), stats fused
    gemm_f16<128, 0, false, true, false><<<dim3(256 / 128, MT), b256, 0, stream>>>(
        yh, wah, z_a, NNODES, 256, 512, nullptr, nullptr, nullptr, nullptr, stA,
        nullptr, nullptr, nullptr);

    // dense1 256->128 (A = BN(z_a)+lrelu in staging), stats fused
    gemm_f16<64, 2, false, true, false><<<dim3(128 / 64, MT), b256, 0, stream>>>(
        z_a, w1h, z_1, NNODES, 128, 256, nullptr, nullptr, nullptr, nullptr, st1,
        stA, g_a, be_a);

    // dense2 128->64 (A = BN(z_1)+lrelu in staging), stats fused
    gemm_f16<64, 2, false, true, false><<<dim3(64 / 64, MT), b256, 0, stream>>>(
        z_1, w2h, z_2, NNODES, 64, 128, nullptr, nullptr, nullptr, nullptr, st2,
        st1, g_1, be_1);

    // BN + lrelu + dense3 fused
    bn_dense3<<<dim3((NNODES + 255) / 256), b256, 0, stream>>>(z_2, st2, g_2, be_2, w_3, b_3, y3);

    // pairwise distances
    dist_kernel<<<dim3((NNODES + 1023) / 1024, (NNODES + 63) / 64), b256, 0, stream>>>(y3, (float*)d_out);
}

// Round 12
// 245.091 us; speedup vs baseline: 1.2463x; 1.0554x over previous
//
#include <hip/hip_runtime.h>
#include <math.h>

#define NNODES 10000
#define NEDGES 320000
#define ETOT   (NEDGES + NNODES)
#define FINF   512
#define HD     512     // H*D
#define MAXDEG 128

typedef __attribute__((ext_vector_type(8))) _Float16 f16x8;
typedef __attribute__((ext_vector_type(8))) ushort u16x8;
typedef __attribute__((ext_vector_type(4))) float f32x4;

__device__ __forceinline__ ushort f2h(float f) {
    return __builtin_bit_cast(ushort, (_Float16)f);
}
__device__ __forceinline__ float h2f(ushort u) {
    return (float)__builtin_bit_cast(_Float16, u);
}

// ------ prep: x -> fp16, transpose 4 weights to fp16 [N][K], zero control block ------
#define XC4 (NNODES * FINF / 4)          // 1,280,000 float4 items of x
#define PW1 (512 * 512)                  // w_conv
#define PW2 (PW1 + 256 * 512)            // w_a
#define PW3 (PW2 + 128 * 256)            // w_1
#define PW4 (PW3 + 64 * 128)             // w_2
#define PTOT (XC4 + PW4)
#define ZWORDS 50896                     // ZB bytes / 4
__global__ __launch_bounds__(256) void prep_kernel(
    const float* __restrict__ x, ushort* __restrict__ xh,
    const float* __restrict__ wc, ushort* __restrict__ wch,
    const float* __restrict__ wa, ushort* __restrict__ wah,
    const float* __restrict__ w1, ushort* __restrict__ w1h,
    const float* __restrict__ w2, ushort* __restrict__ w2h,
    int* __restrict__ zbuf)
{
    int idx = blockIdx.x * 256 + threadIdx.x;
    if (idx >= PTOT) return;
    if (idx < ZWORDS) zbuf[idx] = 0;
    if (idx < XC4) {
        float4 v = ((const float4*)x)[idx];
        ushort4 o;
        o.x = f2h(v.x); o.y = f2h(v.y); o.z = f2h(v.z); o.w = f2h(v.w);
        ((ushort4*)xh)[idx] = o;
        return;
    }
    int widx = idx - XC4;
    float v; ushort* th; int i;
    if (widx < PW1) {           // w_conv [512][512] -> T
        i = widx; int n = i >> 9, k = i & 511;
        v = wc[(size_t)k * 512 + n]; th = wch;
    } else if (widx < PW2) {    // w_a [512][256] -> [256][512]
        i = widx - PW1; int n = i >> 9, k = i & 511;
        v = wa[(size_t)k * 256 + n]; th = wah;
    } else if (widx < PW3) {    // w_1 [256][128] -> [128][256]
        i = widx - PW2; int n = i >> 8, k = i & 255;
        v = w1[(size_t)k * 128 + n]; th = w1h;
    } else {                    // w_2 [128][64] -> [64][128]
        i = widx - PW3; int n = i >> 7, k = i & 127;
        v = w2[(size_t)k * 64 + n]; th = w2h;
    }
    th[i] = f2h(v);
}

// ---------------- fp16-MFMA GEMM with fused A-transform / attn / BN-stats epilogues -------
// AMODE 0: A fp16 [M][K]. AMODE 2: A f32 + BN + lrelu. AMODE 3: A fp16 + BN + lrelu.
// B: fp16 [N][K] (pre-transposed). BK=32, BM=64. 4 waves 2x2; frags MR=2 x NR=BN/32.
// OF16: C written as fp16.
template<int BN, int AMODE, bool ATTN, bool STATS, bool OF16>
__global__ __launch_bounds__(256) void gemm_f16(
    const void* __restrict__ Ain, const ushort* __restrict__ Bh,
    void* __restrict__ Cout, int M, int N, int K,
    const float* __restrict__ att_s, const float* __restrict__ att_d,
    float* __restrict__ a_src, float* __restrict__ a_dst,
    float* __restrict__ stats,
    const float* __restrict__ bnst, const float* __restrict__ bng,
    const float* __restrict__ bnbe)
{
    constexpr int BM = 64;
    constexpr int MR = 2, NR = BN / 32;
    __shared__ ushort sA[BM][40], sB[BN][40];   // 80B row stride: 2-way bank (free)
    __shared__ float bsc[256], bsh[256];        // BN scale/shift (AMODE 2/3, K<=256)
    int tid = threadIdx.x;
    int lane = tid & 63, wave = tid >> 6;
    int wr = wave >> 1, wc = wave & 1;
    int bm = blockIdx.y * BM, bn = blockIdx.x * BN;
    int mrow = lane & 15, kb = lane >> 4;

    if constexpr (AMODE == 2 || AMODE == 3) {
        for (int c = tid; c < K; c += 256) {
            float m = bnst[c] * (1.f / NNODES);
            float var = bnst[K + c] * (1.f / NNODES) - m * m;
            float sc = bng[c] * rsqrtf(var + 1e-5f);
            bsc[c] = sc;
            bsh[c] = bnbe[c] - m * sc;
        }
        __syncthreads();
    }

    int ar = tid >> 2, akc = tid & 3;
    int arow = bm + ar;
    bool aval = arow < M;
    size_t aoff = (size_t)(aval ? arow : 0) * K + akc * 8;
    int br, bkc;
    if constexpr (BN == 128) { br = tid >> 1; bkc = (tid & 1) * 2; }
    else { br = tid >> 2; bkc = tid & 3; }
    size_t boff = (size_t)(bn + br) * K + bkc * 8;

    f32x4 acc[MR][NR];
    #pragma unroll
    for (int i = 0; i < MR; ++i)
        #pragma unroll
        for (int j = 0; j < NR; ++j)
            acc[i][j] = (f32x4){0.f, 0.f, 0.f, 0.f};

    for (int k0 = 0; k0 < K; k0 += 32) {
        int4 va;
        if constexpr (AMODE == 0) {
            va = aval ? *(const int4*)((const ushort*)Ain + aoff + k0) : (int4){0, 0, 0, 0};
        } else if constexpr (AMODE == 3) {
            u16x8 us = (u16x8)0;
            if (aval) {
                u16x8 uin = *(const u16x8*)((const ushort*)Ain + aoff + k0);
                #pragma unroll
                for (int j = 0; j < 8; ++j) {
                    float v = h2f(uin[j]);
                    int c = k0 + akc * 8 + j;
                    v = fmaf(v, bsc[c], bsh[c]);
                    v = (v > 0.f) ? v : 0.01f * v;
                    us[j] = f2h(v);
                }
            }
            va = __builtin_bit_cast(int4, us);
        } else {   // AMODE 2: f32 + BN + lrelu
            u16x8 us = (u16x8)0;
            if (aval) {
                const float* ap = (const float*)Ain + aoff + k0;
                float4 f0 = *(const float4*)ap;
                float4 f1 = *(const float4*)(ap + 4);
                float vv[8] = {f0.x, f0.y, f0.z, f0.w, f1.x, f1.y, f1.z, f1.w};
                #pragma unroll
                for (int j = 0; j < 8; ++j) {
                    float v = vv[j];
                    int c = k0 + akc * 8 + j;
                    v = fmaf(v, bsc[c], bsh[c]);
                    v = (v > 0.f) ? v : 0.01f * v;
                    us[j] = f2h(v);
                }
            }
            va = __builtin_bit_cast(int4, us);
        }
        int4 vb0 = *(const int4*)(Bh + boff + k0);
        int4 vb1;
        if constexpr (BN == 128) vb1 = *(const int4*)(Bh + boff + k0 + 8);
        __syncthreads();
        *(int4*)&sA[ar][akc * 8] = va;
        *(int4*)&sB[br][bkc * 8] = vb0;
        if constexpr (BN == 128) *(int4*)&sB[br][(bkc + 1) * 8] = vb1;
        __syncthreads();

        f16x8 fa[MR], fb[NR];
        #pragma unroll
        for (int fi = 0; fi < MR; ++fi)
            fa[fi] = *(const f16x8*)&sA[wr * 32 + fi * 16 + mrow][kb * 8];
        #pragma unroll
        for (int fj = 0; fj < NR; ++fj)
            fb[fj] = *(const f16x8*)&sB[wc * (BN / 2) + fj * 16 + mrow][kb * 8];
        #pragma unroll
        for (int fi = 0; fi < MR; ++fi)
            #pragma unroll
            for (int fj = 0; fj < NR; ++fj)
                acc[fi][fj] = __builtin_amdgcn_mfma_f32_16x16x32_f16(fa[fi], fb[fj], acc[fi][fj], 0, 0, 0);
    }

    // C write: row = bm + wr*32 + fi*16 + (lane>>4)*4 + r ; col = bn + wc*(BN/2) + fj*16 + mrow
    #pragma unroll
    for (int fi = 0; fi < MR; ++fi) {
        int crow0 = bm + wr * 32 + fi * 16 + (lane >> 4) * 4;
        #pragma unroll
        for (int fj = 0; fj < NR; ++fj) {
            int ccol = bn + wc * (BN / 2) + fj * 16 + mrow;
            #pragma unroll
            for (int r = 0; r < 4; ++r) {
                int row = crow0 + r;
                if (row < M) {
                    if constexpr (OF16)
                        ((ushort*)Cout)[(size_t)row * N + ccol] = f2h(acc[fi][fj][r]);
                    else
                        ((float*)Cout)[(size_t)row * N + ccol] = acc[fi][fj][r];
                }
            }
        }
    }

    if constexpr (ATTN) {
        int hd = bn >> 8;
        float as_v[NR], ad_v[NR];
        #pragma unroll
        for (int fj = 0; fj < NR; ++fj) {
            int c = bn + wc * (BN / 2) + fj * 16 + mrow;
            as_v[fj] = att_s[c];
            ad_v[fj] = att_d[c];
        }
        #pragma unroll
        for (int fi = 0; fi < MR; ++fi)
            #pragma unroll
            for (int r = 0; r < 4; ++r) {
                float ss = 0.f, sd = 0.f;
                #pragma unroll
                for (int fj = 0; fj < NR; ++fj) {
                    float v = acc[fi][fj][r];
                    ss = fmaf(v, as_v[fj], ss);
                    sd = fmaf(v, ad_v[fj], sd);
                }
                #pragma unroll
                for (int off = 1; off < 16; off <<= 1) {
                    ss += __shfl_xor(ss, off);
                    sd += __shfl_xor(sd, off);
                }
                if (mrow == 0) {
                    int row = bm + wr * 32 + fi * 16 + (lane >> 4) * 4 + r;
                    if (row < M) {
                        atomicAdd(&a_src[2 * row + hd], ss);
                        atomicAdd(&a_dst[2 * row + hd], sd);
                    }
                }
            }
    }

    if constexpr (STATS) {
        #pragma unroll
        for (int fj = 0; fj < NR; ++fj) {
            float s = 0.f, s2 = 0.f;
            #pragma unroll
            for (int fi = 0; fi < MR; ++fi)
                #pragma unroll
                for (int r = 0; r < 4; ++r) {
                    float v = acc[fi][fj][r];
                    s += v;
                    s2 = fmaf(v, v, s2);
                }
            s  += __shfl_xor(s, 16);  s  += __shfl_xor(s, 32);
            s2 += __shfl_xor(s2, 16); s2 += __shfl_xor(s2, 32);
            if (lane < 16) {
                int c = bn + wc * (BN / 2) + fj * 16 + lane;
                atomicAdd(&stats[c], s);
                atomicAdd(&stats[N + c], s2);
            }
        }
    }
}

// ---------------- scatter edges into fixed-stride buckets; p = exp(lrelu(e)) ----------
__global__ __launch_bounds__(256) void scatter_kernel(const int* __restrict__ ei,
    const float* __restrict__ a_src, const float* __restrict__ a_dst,
    int* __restrict__ cnt, int* __restrict__ esrc,
    float* __restrict__ p0, float* __restrict__ p1)
{
    int e = blockIdx.x * 256 + threadIdx.x;
    if (e >= ETOT) return;
    int s, d;
    if (e < NEDGES) { s = ei[e]; d = ei[NEDGES + e]; } else { s = d = e - NEDGES; }
    int pos = atomicAdd(&cnt[d], 1);
    if (pos >= MAXDEG) return;   // statistically impossible for this graph
    int slot = d * MAXDEG + pos;
    esrc[slot] = s;
    float e0 = a_src[2 * s] + a_dst[2 * d];
    e0 = (e0 > 0.f) ? e0 : 0.2f * e0;
    float e1 = a_src[2 * s + 1] + a_dst[2 * d + 1];
    e1 = (e1 > 0.f) ? e1 : 0.2f * e1;
    p0[slot] = expf(e0);
    p1[slot] = expf(e1);
}

// ---------------- per-node aggregation (fp16 h) -> lrelu -> fp16 y, unrolled x2 ------
// 128 threads: thread t owns features [4t,4t+4); t<64 = head0 (p0), t>=64 = head1 (p1).
__global__ __launch_bounds__(128) void aggregate_kernel(const ushort* __restrict__ h,
    const int* __restrict__ cnt, const int* __restrict__ esrc,
    const float* __restrict__ p0, const float* __restrict__ p1,
    const float* __restrict__ b_conv, ushort* __restrict__ yh)
{
    int n = blockIdx.x, t = threadIdx.x;
    int len = cnt[n]; if (len > MAXDEG) len = MAXDEG;
    int base = n * MAXDEG;
    const float* pp = (t < 64) ? p0 : p1;
    float a0 = 0.f, a1 = 0.f, a2 = 0.f, a3 = 0.f;
    float den = 0.f;
    int k = 0;
    for (; k + 1 < len; k += 2) {
        int s0 = esrc[base + k], s1 = esrc[base + k + 1];
        float q0 = pp[base + k], q1 = pp[base + k + 1];
        ushort4 hv0 = ((const ushort4*)(h + (size_t)s0 * HD))[t];
        ushort4 hv1 = ((const ushort4*)(h + (size_t)s1 * HD))[t];
        a0 = fmaf(q0, h2f(hv0.x), a0); a1 = fmaf(q0, h2f(hv0.y), a1);
        a2 = fmaf(q0, h2f(hv0.z), a2); a3 = fmaf(q0, h2f(hv0.w), a3);
        a0 = fmaf(q1, h2f(hv1.x), a0); a1 = fmaf(q1, h2f(hv1.y), a1);
        a2 = fmaf(q1, h2f(hv1.z), a2); a3 = fmaf(q1, h2f(hv1.w), a3);
        den += q0 + q1;
    }
    if (k < len) {
        int s0 = esrc[base + k];
        float q0 = pp[base + k];
        ushort4 hv0 = ((const ushort4*)(h + (size_t)s0 * HD))[t];
        a0 = fmaf(q0, h2f(hv0.x), a0); a1 = fmaf(q0, h2f(hv0.y), a1);
        a2 = fmaf(q0, h2f(hv0.z), a2); a3 = fmaf(q0, h2f(hv0.w), a3);
        den += q0;
    }
    float4 bc = *(const float4*)(b_conv + t * 4);
    float inv = 1.f / den;
    float o[4] = { a0 * inv + bc.x, a1 * inv + bc.y, a2 * inv + bc.z, a3 * inv + bc.w };
    ushort4 hq;
    float v;
    v = (o[0] > 0.f) ? o[0] : 0.01f * o[0]; hq.x = f2h(v);
    v = (o[1] > 0.f) ? o[1] : 0.01f * o[1]; hq.y = f2h(v);
    v = (o[2] > 0.f) ? o[2] : 0.01f * o[2]; hq.z = f2h(v);
    v = (o[3] > 0.f) ? o[3] : 0.01f * o[3]; hq.w = f2h(v);
    ((ushort4*)(yh + (size_t)n * HD))[t] = hq;
}

// ---------------- BN(64) + lrelu + dense3 fused -> y3 ----------------
__global__ __launch_bounds__(256) void bn_dense3(const float* __restrict__ z2,
    const float* __restrict__ st, const float* __restrict__ g, const float* __restrict__ beta,
    const float* __restrict__ w3, const float* __restrict__ b3, float* __restrict__ y3)
{
    __shared__ float wsm[192], msm[64], rsm[64], gsm[64], bsm[64];
    int t = threadIdx.x;
    if (t < 192) wsm[t] = w3[t];
    if (t < 64) {
        float m = st[t] * (1.f / NNODES);
        float v = st[64 + t] * (1.f / NNODES) - m * m;
        msm[t] = m; rsm[t] = rsqrtf(v + 1e-5f);
        gsm[t] = g[t]; bsm[t] = beta[t];
    }
    __syncthreads();
    int n = blockIdx.x * 256 + t;
    if (n >= NNODES) return;
    const float* zr = z2 + (size_t)n * 64;
    float o0 = b3[0], o1 = b3[1], o2 = b3[2];
    #pragma unroll
    for (int c = 0; c < 64; ++c) {
        float xv = zr[c];
        xv = gsm[c] * (xv - msm[c]) * rsm[c] + bsm[c];
        xv = (xv > 0.f) ? xv : 0.01f * xv;
        o0 = fmaf(xv, wsm[3 * c],     o0);
        o1 = fmaf(xv, wsm[3 * c + 1], o1);
        o2 = fmaf(xv, wsm[3 * c + 2], o2);
    }
    y3[3 * n] = o0; y3[3 * n + 1] = o1; y3[3 * n + 2] = o2;
}

// ---------------- pairwise euclidean distances [N,N], 4 cols/thread, NT f32x4 stores ----
__global__ __launch_bounds__(256) void dist_kernel(const float* __restrict__ y3, float* __restrict__ out)
{
    int j0 = (blockIdx.x * 256 + threadIdx.x) * 4;
    int i0 = blockIdx.y * 64;
    if (j0 >= NNODES) return;
    const float4* yp = (const float4*)(y3 + 3 * j0);
    float4 q0 = yp[0], q1 = yp[1], q2 = yp[2];
    float xj[4] = {q0.x, q0.w, q1.z, q2.y};
    float yj[4] = {q0.y, q1.x, q1.w, q2.z};
    float zj[4] = {q0.z, q1.y, q2.x, q2.w};
    int iend = (i0 + 64 < NNODES) ? (i0 + 64) : NNODES;
    for (int i = i0; i < iend; ++i) {
        float xi = y3[3 * i], yi = y3[3 * i + 1], zi = y3[3 * i + 2];
        f32x4 dv;
        #pragma unroll
        for (int u = 0; u < 4; ++u) {
            float dx = xi - xj[u], dy = yi - yj[u], dz = zi - zj[u];
            float d2 = fmaf(dx, dx, fmaf(dy, dy, dz * dz));
            dv[u] = (d2 > 1e-12f) ? sqrtf(d2) : 0.f;
        }
        __builtin_nontemporal_store(dv, (f32x4*)(out + (size_t)i * NNODES + j0));
    }
}

extern "C" void kernel_launch(void* const* d_in, const int* in_sizes, int n_in,
                              void* d_out, int out_size, void* d_ws, size_t ws_size,
                              hipStream_t stream)
{
    (void)in_sizes; (void)n_in; (void)out_size; (void)ws_size;
    const float* x      = (const float*)d_in[0];
    const int*   ei     = (const int*)  d_in[1];
    const float* w_conv = (const float*)d_in[2];
    const float* att_s  = (const float*)d_in[3];
    const float* att_d  = (const float*)d_in[4];
    const float* b_conv = (const float*)d_in[5];
    const float* w_a  = (const float*)d_in[6];
    const float* g_a  = (const float*)d_in[8];
    const float* be_a = (const float*)d_in[9];
    const float* w_1  = (const float*)d_in[10];
    const float* g_1  = (const float*)d_in[12];
    const float* be_1 = (const float*)d_in[13];
    const float* w_2  = (const float*)d_in[14];
    const float* g_2  = (const float*)d_in[16];
    const float* be_2 = (const float*)d_in[17];
    const float* w_3  = (const float*)d_in[18];
    const float* b_3  = (const float*)d_in[19];

    char* ws = (char*)d_ws;
    size_t off = 0;
    auto take = [&](size_t bytes) {
        char* p = ws + off;
        off = (off + bytes + 255) & ~(size_t)255;
        return p;
    };
    ushort* h   = (ushort*)take((size_t)NNODES * HD * 2);      // fp16 h
    ushort* yh  = (ushort*)take((size_t)NNODES * HD * 2);      // fp16 y
    ushort* xh  = (ushort*)take((size_t)NNODES * FINF * 2);    // fp16 x
    ushort* z_a = (ushort*)take((size_t)NNODES * 256 * 2);     // fp16 z_a
    ushort* z_1 = (ushort*)take((size_t)NNODES * 128 * 2);     // fp16 z_1
    float* z_2  = (float*)take((size_t)NNODES * 64 * 4);
    float* y3   = (float*)take((size_t)NNODES * 3 * 4);
    ushort* wch = (ushort*)take((size_t)512 * 512 * 2);
    ushort* wah = (ushort*)take((size_t)256 * 512 * 2);
    ushort* w1h = (ushort*)take((size_t)128 * 256 * 2);
    ushort* w2h = (ushort*)take((size_t)64 * 128 * 2);
    int*   esrc = (int*)  take((size_t)NNODES * MAXDEG * 4);
    float* p0   = (float*)take((size_t)NNODES * MAXDEG * 4);
    float* p1   = (float*)take((size_t)NNODES * MAXDEG * 4);
    // zeroed-by-prep block: cnt, stats x3, a_src, a_dst  (ZWORDS*4 bytes total)
    const size_t ZB = 40000 + 2048 + 1024 + 512 + 80000 + 80000;   // 203584 = 50896*4
    char*  zblk = take(ZB);
    int*   cnt  = (int*)(zblk);
    float* stA  = (float*)(zblk + 40000);
    float* st1  = (float*)(zblk + 42048);
    float* st2  = (float*)(zblk + 43072);
    float* a_src= (float*)(zblk + 43584);
    float* a_dst= (float*)(zblk + 123584);

    dim3 b256(256), b128(128);
    const int MT = (NNODES + 63) / 64;   // 157

    // x -> fp16, weights -> fp16 transposed, zero control block
    prep_kernel<<<dim3((PTOT + 255) / 256), b256, 0, stream>>>(
        x, xh, w_conv, wch, w_a, wah, w_1, w1h, w_2, w2h, (int*)zblk);

    // h = xh @ w_conv^T (fp16 out), fused attn coefficients
    gemm_f16<128, 0, true, false, true><<<dim3(HD / 128, MT), b256, 0, stream>>>(
        xh, wch, h, NNODES, HD, FINF, att_s, att_d, a_src, a_dst, nullptr,
        nullptr, nullptr, nullptr);

    scatter_kernel<<<dim3((ETOT + 255) / 256), b256, 0, stream>>>(
        ei, a_src, a_dst, cnt, esrc, p0, p1);

    aggregate_kernel<<<dim3(NNODES), b128, 0, stream>>>(
        h, cnt, esrc, p0, p1, b_conv, yh);

    // densea 512->256 (A = y fp16), stats fused, z_a fp16
    gemm_f16<128, 0, false, true, true><<<dim3(256 / 128, MT), b256, 0, stream>>>(
        yh, wah, z_a, NNODES, 256, 512, nullptr, nullptr, nullptr, nullptr, stA,
        nullptr, nullptr, nullptr);

    // dense1 256->128 (A = BN(z_a fp16)+lrelu in staging), stats fused, z_1 fp16
    gemm_f16<64, 3, false, true, true><<<dim3(128 / 64, MT), b256, 0, stream>>>(
        z_a, w1h, z_1, NNODES, 128, 256, nullptr, nullptr, nullptr, nullptr, st1,
        stA, g_a, be_a);

    // dense2 128->64 (A = BN(z_1 fp16)+lrelu in staging), stats fused, z_2 f32
    gemm_f16<64, 3, false, true, false><<<dim3(64 / 64, MT), b256, 0, stream>>>(
        z_1, w2h, z_2, NNODES, 64, 128, nullptr, nullptr, nullptr, nullptr, st2,
        st1, g_1, be_1);

    // BN + lrelu + dense3 fused
    bn_dense3<<<dim3((NNODES + 255) / 256), b256, 0, stream>>>(z_2, st2, g_2, be_2, w_3, b_3, y3);

    // pairwise distances
    dist_kernel<<<dim3((NNODES + 1023) / 1024, (NNODES + 63) / 64), b256, 0, stream>>>(y3, (float*)d_out);
}

// Round 13
// 242.366 us; speedup vs baseline: 1.2603x; 1.0112x over previous
//
#include <hip/hip_runtime.h>
#include <math.h>

#define NNODES 10000
#define NEDGES 320000
#define ETOT   (NEDGES + NNODES)
#define FINF   512
#define HD     512     // H*D
#define MAXDEG 128

typedef __attribute__((ext_vector_type(8))) _Float16 f16x8;
typedef __attribute__((ext_vector_type(8))) ushort u16x8;
typedef __attribute__((ext_vector_type(4))) float f32x4;

__device__ __forceinline__ ushort f2h(float f) {
    return __builtin_bit_cast(ushort, (_Float16)f);
}
__device__ __forceinline__ float h2f(ushort u) {
    return (float)__builtin_bit_cast(_Float16, u);
}

// ------ prep: x -> fp16, transpose 4 weights to fp16 [N][K], zero control block ------
#define XC4 (NNODES * FINF / 4)          // 1,280,000 float4 items of x
#define PW1 (512 * 512)                  // w_conv
#define PW2 (PW1 + 256 * 512)            // w_a
#define PW3 (PW2 + 128 * 256)            // w_1
#define PW4 (PW3 + 64 * 128)             // w_2
#define PTOT (XC4 + PW4)
#define ZWORDS 50896                     // ZB bytes / 4
__global__ __launch_bounds__(256) void prep_kernel(
    const float* __restrict__ x, ushort* __restrict__ xh,
    const float* __restrict__ wc, ushort* __restrict__ wch,
    const float* __restrict__ wa, ushort* __restrict__ wah,
    const float* __restrict__ w1, ushort* __restrict__ w1h,
    const float* __restrict__ w2, ushort* __restrict__ w2h,
    int* __restrict__ zbuf)
{
    int idx = blockIdx.x * 256 + threadIdx.x;
    if (idx >= PTOT) return;
    if (idx < ZWORDS) zbuf[idx] = 0;
    if (idx < XC4) {
        float4 v = ((const float4*)x)[idx];
        ushort4 o;
        o.x = f2h(v.x); o.y = f2h(v.y); o.z = f2h(v.z); o.w = f2h(v.w);
        ((ushort4*)xh)[idx] = o;
        return;
    }
    int widx = idx - XC4;
    float v; ushort* th; int i;
    if (widx < PW1) {           // w_conv [512][512] -> T
        i = widx; int n = i >> 9, k = i & 511;
        v = wc[(size_t)k * 512 + n]; th = wch;
    } else if (widx < PW2) {    // w_a [512][256] -> [256][512]
        i = widx - PW1; int n = i >> 9, k = i & 511;
        v = wa[(size_t)k * 256 + n]; th = wah;
    } else if (widx < PW3) {    // w_1 [256][128] -> [128][256]
        i = widx - PW2; int n = i >> 8, k = i & 255;
        v = w1[(size_t)k * 128 + n]; th = w1h;
    } else {                    // w_2 [128][64] -> [64][128]
        i = widx - PW3; int n = i >> 7, k = i & 127;
        v = w2[(size_t)k * 64 + n]; th = w2h;
    }
    th[i] = f2h(v);
}

// ---------------- fp16-MFMA GEMM with fused A-transform / attn / BN-stats epilogues -------
// AMODE 0: A fp16 [M][K]. AMODE 3: A fp16 + BN + lrelu in staging.
// B: fp16 [N][K] (pre-transposed). BK=32, BM=64. 4 waves 2x2; frags MR=2 x NR=BN/32.
// OF16: C written as fp16.
template<int BN, int AMODE, bool ATTN, bool STATS, bool OF16>
__global__ __launch_bounds__(256) void gemm_f16(
    const void* __restrict__ Ain, const ushort* __restrict__ Bh,
    void* __restrict__ Cout, int M, int N, int K,
    const float* __restrict__ att_s, const float* __restrict__ att_d,
    float* __restrict__ a_src, float* __restrict__ a_dst,
    float* __restrict__ stats,
    const float* __restrict__ bnst, const float* __restrict__ bng,
    const float* __restrict__ bnbe)
{
    constexpr int BM = 64;
    constexpr int MR = 2, NR = BN / 32;
    __shared__ ushort sA[BM][40], sB[BN][40];   // 80B row stride: 2-way bank (free)
    __shared__ float bsc[256], bsh[256];        // BN scale/shift (AMODE 3, K<=256)
    int tid = threadIdx.x;
    int lane = tid & 63, wave = tid >> 6;
    int wr = wave >> 1, wc = wave & 1;
    int bm = blockIdx.y * BM, bn = blockIdx.x * BN;
    int mrow = lane & 15, kb = lane >> 4;

    if constexpr (AMODE == 3) {
        for (int c = tid; c < K; c += 256) {
            float m = bnst[c] * (1.f / NNODES);
            float var = bnst[K + c] * (1.f / NNODES) - m * m;
            float sc = bng[c] * rsqrtf(var + 1e-5f);
            bsc[c] = sc;
            bsh[c] = bnbe[c] - m * sc;
        }
        __syncthreads();
    }

    int ar = tid >> 2, akc = tid & 3;
    int arow = bm + ar;
    bool aval = arow < M;
    size_t aoff = (size_t)(aval ? arow : 0) * K + akc * 8;
    int br, bkc;
    if constexpr (BN == 128) { br = tid >> 1; bkc = (tid & 1) * 2; }
    else { br = tid >> 2; bkc = tid & 3; }
    size_t boff = (size_t)(bn + br) * K + bkc * 8;

    f32x4 acc[MR][NR];
    #pragma unroll
    for (int i = 0; i < MR; ++i)
        #pragma unroll
        for (int j = 0; j < NR; ++j)
            acc[i][j] = (f32x4){0.f, 0.f, 0.f, 0.f};

    for (int k0 = 0; k0 < K; k0 += 32) {
        int4 va;
        if constexpr (AMODE == 0) {
            va = aval ? *(const int4*)((const ushort*)Ain + aoff + k0) : (int4){0, 0, 0, 0};
        } else {   // AMODE 3: fp16 + BN + lrelu
            u16x8 us = (u16x8)0;
            if (aval) {
                u16x8 uin = *(const u16x8*)((const ushort*)Ain + aoff + k0);
                #pragma unroll
                for (int j = 0; j < 8; ++j) {
                    float v = h2f(uin[j]);
                    int c = k0 + akc * 8 + j;
                    v = fmaf(v, bsc[c], bsh[c]);
                    v = (v > 0.f) ? v : 0.01f * v;
                    us[j] = f2h(v);
                }
            }
            va = __builtin_bit_cast(int4, us);
        }
        int4 vb0 = *(const int4*)(Bh + boff + k0);
        int4 vb1;
        if constexpr (BN == 128) vb1 = *(const int4*)(Bh + boff + k0 + 8);
        __syncthreads();
        *(int4*)&sA[ar][akc * 8] = va;
        *(int4*)&sB[br][bkc * 8] = vb0;
        if constexpr (BN == 128) *(int4*)&sB[br][(bkc + 1) * 8] = vb1;
        __syncthreads();

        f16x8 fa[MR], fb[NR];
        #pragma unroll
        for (int fi = 0; fi < MR; ++fi)
            fa[fi] = *(const f16x8*)&sA[wr * 32 + fi * 16 + mrow][kb * 8];
        #pragma unroll
        for (int fj = 0; fj < NR; ++fj)
            fb[fj] = *(const f16x8*)&sB[wc * (BN / 2) + fj * 16 + mrow][kb * 8];
        #pragma unroll
        for (int fi = 0; fi < MR; ++fi)
            #pragma unroll
            for (int fj = 0; fj < NR; ++fj)
                acc[fi][fj] = __builtin_amdgcn_mfma_f32_16x16x32_f16(fa[fi], fb[fj], acc[fi][fj], 0, 0, 0);
    }

    // C write: row = bm + wr*32 + fi*16 + (lane>>4)*4 + r ; col = bn + wc*(BN/2) + fj*16 + mrow
    #pragma unroll
    for (int fi = 0; fi < MR; ++fi) {
        int crow0 = bm + wr * 32 + fi * 16 + (lane >> 4) * 4;
        #pragma unroll
        for (int fj = 0; fj < NR; ++fj) {
            int ccol = bn + wc * (BN / 2) + fj * 16 + mrow;
            #pragma unroll
            for (int r = 0; r < 4; ++r) {
                int row = crow0 + r;
                if (row < M) {
                    if constexpr (OF16)
                        ((ushort*)Cout)[(size_t)row * N + ccol] = f2h(acc[fi][fj][r]);
                    else
                        ((float*)Cout)[(size_t)row * N + ccol] = acc[fi][fj][r];
                }
            }
        }
    }

    if constexpr (ATTN) {
        int hd = bn >> 8;
        float as_v[NR], ad_v[NR];
        #pragma unroll
        for (int fj = 0; fj < NR; ++fj) {
            int c = bn + wc * (BN / 2) + fj * 16 + mrow;
            as_v[fj] = att_s[c];
            ad_v[fj] = att_d[c];
        }
        #pragma unroll
        for (int fi = 0; fi < MR; ++fi)
            #pragma unroll
            for (int r = 0; r < 4; ++r) {
                float ss = 0.f, sd = 0.f;
                #pragma unroll
                for (int fj = 0; fj < NR; ++fj) {
                    float v = acc[fi][fj][r];
                    ss = fmaf(v, as_v[fj], ss);
                    sd = fmaf(v, ad_v[fj], sd);
                }
                #pragma unroll
                for (int off = 1; off < 16; off <<= 1) {
                    ss += __shfl_xor(ss, off);
                    sd += __shfl_xor(sd, off);
                }
                if (mrow == 0) {
                    int row = bm + wr * 32 + fi * 16 + (lane >> 4) * 4 + r;
                    if (row < M) {
                        atomicAdd(&a_src[2 * row + hd], ss);
                        atomicAdd(&a_dst[2 * row + hd], sd);
                    }
                }
            }
    }

    if constexpr (STATS) {
        #pragma unroll
        for (int fj = 0; fj < NR; ++fj) {
            float s = 0.f, s2 = 0.f;
            #pragma unroll
            for (int fi = 0; fi < MR; ++fi)
                #pragma unroll
                for (int r = 0; r < 4; ++r) {
                    float v = acc[fi][fj][r];
                    s += v;
                    s2 = fmaf(v, v, s2);
                }
            s  += __shfl_xor(s, 16);  s  += __shfl_xor(s, 32);
            s2 += __shfl_xor(s2, 16); s2 += __shfl_xor(s2, 32);
            if (lane < 16) {
                int c = bn + wc * (BN / 2) + fj * 16 + lane;
                atomicAdd(&stats[c], s);
                atomicAdd(&stats[N + c], s2);
            }
        }
    }
}

// ---------------- scatter edges into fixed-stride buckets; p = exp(lrelu(e)) ----------
__global__ __launch_bounds__(256) void scatter_kernel(const int* __restrict__ ei,
    const float* __restrict__ a_src, const float* __restrict__ a_dst,
    int* __restrict__ cnt, int* __restrict__ esrc,
    float* __restrict__ p0, float* __restrict__ p1)
{
    int e = blockIdx.x * 256 + threadIdx.x;
    if (e >= ETOT) return;
    int s, d;
    if (e < NEDGES) { s = ei[e]; d = ei[NEDGES + e]; } else { s = d = e - NEDGES; }
    int pos = atomicAdd(&cnt[d], 1);
    if (pos >= MAXDEG) return;   // statistically impossible for this graph
    int slot = d * MAXDEG + pos;
    esrc[slot] = s;
    float e0 = a_src[2 * s] + a_dst[2 * d];
    e0 = (e0 > 0.f) ? e0 : 0.2f * e0;
    float e1 = a_src[2 * s + 1] + a_dst[2 * d + 1];
    e1 = (e1 > 0.f) ? e1 : 0.2f * e1;
    p0[slot] = expf(e0);
    p1[slot] = expf(e1);
}

// ---------------- per-node aggregation (fp16 h) -> lrelu -> fp16 y, unrolled x4 ------
// 128 threads: thread t owns features [4t,4t+4); t<64 = head0 (p0), t>=64 = head1 (p1).
__global__ __launch_bounds__(128) void aggregate_kernel(const ushort* __restrict__ h,
    const int* __restrict__ cnt, const int* __restrict__ esrc,
    const float* __restrict__ p0, const float* __restrict__ p1,
    const float* __restrict__ b_conv, ushort* __restrict__ yh)
{
    int n = blockIdx.x, t = threadIdx.x;
    int len = cnt[n]; if (len > MAXDEG) len = MAXDEG;
    int base = n * MAXDEG;
    const float* pp = (t < 64) ? p0 : p1;
    float a0 = 0.f, a1 = 0.f, a2 = 0.f, a3 = 0.f;
    float den = 0.f;
    int k = 0;
    for (; k + 3 < len; k += 4) {
        int s0 = esrc[base + k],     s1 = esrc[base + k + 1];
        int s2 = esrc[base + k + 2], s3 = esrc[base + k + 3];
        float q0 = pp[base + k],     q1 = pp[base + k + 1];
        float q2 = pp[base + k + 2], q3 = pp[base + k + 3];
        ushort4 hv0 = ((const ushort4*)(h + (size_t)s0 * HD))[t];
        ushort4 hv1 = ((const ushort4*)(h + (size_t)s1 * HD))[t];
        ushort4 hv2 = ((const ushort4*)(h + (size_t)s2 * HD))[t];
        ushort4 hv3 = ((const ushort4*)(h + (size_t)s3 * HD))[t];
        a0 = fmaf(q0, h2f(hv0.x), a0); a1 = fmaf(q0, h2f(hv0.y), a1);
        a2 = fmaf(q0, h2f(hv0.z), a2); a3 = fmaf(q0, h2f(hv0.w), a3);
        a0 = fmaf(q1, h2f(hv1.x), a0); a1 = fmaf(q1, h2f(hv1.y), a1);
        a2 = fmaf(q1, h2f(hv1.z), a2); a3 = fmaf(q1, h2f(hv1.w), a3);
        a0 = fmaf(q2, h2f(hv2.x), a0); a1 = fmaf(q2, h2f(hv2.y), a1);
        a2 = fmaf(q2, h2f(hv2.z), a2); a3 = fmaf(q2, h2f(hv2.w), a3);
        a0 = fmaf(q3, h2f(hv3.x), a0); a1 = fmaf(q3, h2f(hv3.y), a1);
        a2 = fmaf(q3, h2f(hv3.z), a2); a3 = fmaf(q3, h2f(hv3.w), a3);
        den += (q0 + q1) + (q2 + q3);
    }
    for (; k < len; ++k) {
        int s0 = esrc[base + k];
        float q0 = pp[base + k];
        ushort4 hv0 = ((const ushort4*)(h + (size_t)s0 * HD))[t];
        a0 = fmaf(q0, h2f(hv0.x), a0); a1 = fmaf(q0, h2f(hv0.y), a1);
        a2 = fmaf(q0, h2f(hv0.z), a2); a3 = fmaf(q0, h2f(hv0.w), a3);
        den += q0;
    }
    float4 bc = *(const float4*)(b_conv + t * 4);
    float inv = 1.f / den;
    float o[4] = { a0 * inv + bc.x, a1 * inv + bc.y, a2 * inv + bc.z, a3 * inv + bc.w };
    ushort4 hq;
    float v;
    v = (o[0] > 0.f) ? o[0] : 0.01f * o[0]; hq.x = f2h(v);
    v = (o[1] > 0.f) ? o[1] : 0.01f * o[1]; hq.y = f2h(v);
    v = (o[2] > 0.f) ? o[2] : 0.01f * o[2]; hq.z = f2h(v);
    v = (o[3] > 0.f) ? o[3] : 0.01f * o[3]; hq.w = f2h(v);
    ((ushort4*)(yh + (size_t)n * HD))[t] = hq;
}

// ---------------- BN(64) + lrelu + dense3 fused -> y3 (z2 fp16) ----------------
__global__ __launch_bounds__(256) void bn_dense3(const ushort* __restrict__ z2,
    const float* __restrict__ st, const float* __restrict__ g, const float* __restrict__ beta,
    const float* __restrict__ w3, const float* __restrict__ b3, float* __restrict__ y3)
{
    __shared__ float wsm[192], msm[64], rsm[64], gsm[64], bsm[64];
    int t = threadIdx.x;
    if (t < 192) wsm[t] = w3[t];
    if (t < 64) {
        float m = st[t] * (1.f / NNODES);
        float v = st[64 + t] * (1.f / NNODES) - m * m;
        msm[t] = m; rsm[t] = rsqrtf(v + 1e-5f);
        gsm[t] = g[t]; bsm[t] = beta[t];
    }
    __syncthreads();
    int n = blockIdx.x * 256 + t;
    if (n >= NNODES) return;
    const ushort* zr = z2 + (size_t)n * 64;
    float o0 = b3[0], o1 = b3[1], o2 = b3[2];
    #pragma unroll
    for (int c = 0; c < 64; ++c) {
        float xv = h2f(zr[c]);
        xv = gsm[c] * (xv - msm[c]) * rsm[c] + bsm[c];
        xv = (xv > 0.f) ? xv : 0.01f * xv;
        o0 = fmaf(xv, wsm[3 * c],     o0);
        o1 = fmaf(xv, wsm[3 * c + 1], o1);
        o2 = fmaf(xv, wsm[3 * c + 2], o2);
    }
    y3[3 * n] = o0; y3[3 * n + 1] = o1; y3[3 * n + 2] = o2;
}

// ------- pairwise distances [N,N], 4 cols/thread, i-unroll x2, NT f32x4 stores -------
__global__ __launch_bounds__(256) void dist_kernel(const float* __restrict__ y3, float* __restrict__ out)
{
    int j0 = (blockIdx.x * 256 + threadIdx.x) * 4;
    int i0 = blockIdx.y * 64;
    if (j0 >= NNODES) return;
    const float4* yp = (const float4*)(y3 + 3 * j0);
    float4 q0 = yp[0], q1 = yp[1], q2 = yp[2];
    float xj[4] = {q0.x, q0.w, q1.z, q2.y};
    float yj[4] = {q0.y, q1.x, q1.w, q2.z};
    float zj[4] = {q0.z, q1.y, q2.x, q2.w};
    int iend = (i0 + 64 < NNODES) ? (i0 + 64) : NNODES;
    int i = i0;
    for (; i + 1 < iend; i += 2) {
        float xa = y3[3 * i],     ya = y3[3 * i + 1], za = y3[3 * i + 2];
        float xb = y3[3 * i + 3], yb = y3[3 * i + 4], zb = y3[3 * i + 5];
        f32x4 da, db;
        #pragma unroll
        for (int u = 0; u < 4; ++u) {
            float dx = xa - xj[u], dy = ya - yj[u], dz = za - zj[u];
            float d2 = fmaf(dx, dx, fmaf(dy, dy, dz * dz));
            da[u] = (d2 > 1e-12f) ? sqrtf(d2) : 0.f;
            float ex = xb - xj[u], ey = yb - yj[u], ez = zb - zj[u];
            float e2 = fmaf(ex, ex, fmaf(ey, ey, ez * ez));
            db[u] = (e2 > 1e-12f) ? sqrtf(e2) : 0.f;
        }
        __builtin_nontemporal_store(da, (f32x4*)(out + (size_t)i * NNODES + j0));
        __builtin_nontemporal_store(db, (f32x4*)(out + (size_t)(i + 1) * NNODES + j0));
    }
    if (i < iend) {
        float xa = y3[3 * i], ya = y3[3 * i + 1], za = y3[3 * i + 2];
        f32x4 da;
        #pragma unroll
        for (int u = 0; u < 4; ++u) {
            float dx = xa - xj[u], dy = ya - yj[u], dz = za - zj[u];
            float d2 = fmaf(dx, dx, fmaf(dy, dy, dz * dz));
            da[u] = (d2 > 1e-12f) ? sqrtf(d2) : 0.f;
        }
        __builtin_nontemporal_store(da, (f32x4*)(out + (size_t)i * NNODES + j0));
    }
}

extern "C" void kernel_launch(void* const* d_in, const int* in_sizes, int n_in,
                              void* d_out, int out_size, void* d_ws, size_t ws_size,
                              hipStream_t stream)
{
    (void)in_sizes; (void)n_in; (void)out_size; (void)ws_size;
    const float* x      = (const float*)d_in[0];
    const int*   ei     = (const int*)  d_in[1];
    const float* w_conv = (const float*)d_in[2];
    const float* att_s  = (const float*)d_in[3];
    const float* att_d  = (const float*)d_in[4];
    const float* b_conv = (const float*)d_in[5];
    const float* w_a  = (const float*)d_in[6];
    const float* g_a  = (const float*)d_in[8];
    const float* be_a = (const float*)d_in[9];
    const float* w_1  = (const float*)d_in[10];
    const float* g_1  = (const float*)d_in[12];
    const float* be_1 = (const float*)d_in[13];
    const float* w_2  = (const float*)d_in[14];
    const float* g_2  = (const float*)d_in[16];
    const float* be_2 = (const float*)d_in[17];
    const float* w_3  = (const float*)d_in[18];
    const float* b_3  = (const float*)d_in[19];

    char* ws = (char*)d_ws;
    size_t off = 0;
    auto take = [&](size_t bytes) {
        char* p = ws + off;
        off = (off + bytes + 255) & ~(size_t)255;
        return p;
    };
    ushort* h   = (ushort*)take((size_t)NNODES * HD * 2);      // fp16 h
    ushort* yh  = (ushort*)take((size_t)NNODES * HD * 2);      // fp16 y
    ushort* xh  = (ushort*)take((size_t)NNODES * FINF * 2);    // fp16 x
    ushort* z_a = (ushort*)take((size_t)NNODES * 256 * 2);     // fp16 z_a
    ushort* z_1 = (ushort*)take((size_t)NNODES * 128 * 2);     // fp16 z_1
    ushort* z_2 = (ushort*)take((size_t)NNODES * 64 * 2);      // fp16 z_2
    float* y3   = (float*)take((size_t)NNODES * 3 * 4);
    ushort* wch = (ushort*)take((size_t)512 * 512 * 2);
    ushort* wah = (ushort*)take((size_t)256 * 512 * 2);
    ushort* w1h = (ushort*)take((size_t)128 * 256 * 2);
    ushort* w2h = (ushort*)take((size_t)64 * 128 * 2);
    int*   esrc = (int*)  take((size_t)NNODES * MAXDEG * 4);
    float* p0   = (float*)take((size_t)NNODES * MAXDEG * 4);
    float* p1   = (float*)take((size_t)NNODES * MAXDEG * 4);
    // zeroed-by-prep block: cnt, stats x3, a_src, a_dst  (ZWORDS*4 bytes total)
    const size_t ZB = 40000 + 2048 + 1024 + 512 + 80000 + 80000;   // 203584 = 50896*4
    char*  zblk = take(ZB);
    int*   cnt  = (int*)(zblk);
    float* stA  = (float*)(zblk + 40000);
    float* st1  = (float*)(zblk + 42048);
    float* st2  = (float*)(zblk + 43072);
    float* a_src= (float*)(zblk + 43584);
    float* a_dst= (float*)(zblk + 123584);

    dim3 b256(256), b128(128);
    const int MT = (NNODES + 63) / 64;   // 157

    // x -> fp16, weights -> fp16 transposed, zero control block
    prep_kernel<<<dim3((PTOT + 255) / 256), b256, 0, stream>>>(
        x, xh, w_conv, wch, w_a, wah, w_1, w1h, w_2, w2h, (int*)zblk);

    // h = xh @ w_conv^T (fp16 out), fused attn coefficients
    gemm_f16<128, 0, true, false, true><<<dim3(HD / 128, MT), b256, 0, stream>>>(
        xh, wch, h, NNODES, HD, FINF, att_s, att_d, a_src, a_dst, nullptr,
        nullptr, nullptr, nullptr);

    scatter_kernel<<<dim3((ETOT + 255) / 256), b256, 0, stream>>>(
        ei, a_src, a_dst, cnt, esrc, p0, p1);

    aggregate_kernel<<<dim3(NNODES), b128, 0, stream>>>(
        h, cnt, esrc, p0, p1, b_conv, yh);

    // densea 512->256 (A = y fp16), stats fused, z_a fp16
    gemm_f16<128, 0, false, true, true><<<dim3(256 / 128, MT), b256, 0, stream>>>(
        yh, wah, z_a, NNODES, 256, 512, nullptr, nullptr, nullptr, nullptr, stA,
        nullptr, nullptr, nullptr);

    // dense1 256->128 (A = BN(z_a fp16)+lrelu in staging), stats fused, z_1 fp16
    gemm_f16<64, 3, false, true, true><<<dim3(128 / 64, MT), b256, 0, stream>>>(
        z_a, w1h, z_1, NNODES, 128, 256, nullptr, nullptr, nullptr, nullptr, st1,
        stA, g_a, be_a);

    // dense2 128->64 (A = BN(z_1 fp16)+lrelu in staging), stats fused, z_2 fp16
    gemm_f16<64, 3, false, true, true><<<dim3(64 / 64, MT), b256, 0, stream>>>(
        z_1, w2h, z_2, NNODES, 64, 128, nullptr, nullptr, nullptr, nullptr, st2,
        st1, g_1, be_1);

    // BN + lrelu + dense3 fused
    bn_dense3<<<dim3((NNODES + 255) / 256), b256, 0, stream>>>(z_2, st2, g_2, be_2, w_3, b_3, y3);

    // pairwise distances
    dist_kernel<<<dim3((NNODES + 1023) / 1024, (NNODES + 63) / 64), b256, 0, stream>>>(y3, (float*)d_out);
}